// Round 20
// baseline (157.550 us; speedup 1.0000x reference)
//
#include <hip/hip_runtime.h>

// CausalSelfAttention: B=4, T=2048, C=1024, H=16, D=64
// Pipeline: fused prep (x->bf16 + both weight transposes)
//           -> qkv GEMM (BK=64 dbuf, XCD + 8x4 L2 supertile, NT epilogue stores)
//           -> flash attn (swapped 32x32, KVBLK=64, fixed-shift, l-via-MFMA,
//              3-buffer single-barrier, NT out) -> proj GEMM

typedef unsigned short u16b;
typedef __bf16 bf16x8 __attribute__((ext_vector_type(8)));
typedef float f32x4 __attribute__((ext_vector_type(4)));
typedef float f32x16 __attribute__((ext_vector_type(16)));
typedef unsigned short u16x4 __attribute__((ext_vector_type(4)));

#define AS1(p) ((const __attribute__((address_space(1))) void*)(p))
#define AS3(p) ((__attribute__((address_space(3))) void*)(p))
#define GLDS(g, l) __builtin_amdgcn_global_load_lds(AS1(g), AS3(l), 16, 0, 0)

__device__ __forceinline__ u16b bfr(float v) {  // f32 -> bf16 bits, RNE
  union { float f; unsigned u; } x; x.f = v;
  unsigned r = x.u + 0x7fffu + ((x.u >> 16) & 1u);
  return (u16b)(r >> 16);
}

__device__ __forceinline__ unsigned pk2(float lo, float hi) {  // pack 2 f32 -> 2 bf16 in u32
  union { __bf16 h[2]; unsigned u; } t;
  t.h[0] = (__bf16)lo; t.h[1] = (__bf16)hi;
  return t.u;
}

// ---------------- fused prep: x cvt (blocks 0..2047) + w transposes (2048..3071) ----------------
__global__ __launch_bounds__(256) void prep_kernel(
    const float* __restrict__ x, u16b* __restrict__ xb,
    const float* __restrict__ w_attn, u16b* __restrict__ waT,
    const float* __restrict__ w_proj, u16b* __restrict__ wpT) {
  __shared__ u16b tile[64][72];
  const int bid = blockIdx.x;
  if (bid < 2048) {
    const int n4 = (8192 * 1024) / 4;
    const int stride = 2048 * 256;
    for (int i = bid * 256 + threadIdx.x; i < n4; i += stride) {
      const float4 v = reinterpret_cast<const float4*>(x)[i];
      u16x4 o;
      o[0] = bfr(v.x); o[1] = bfr(v.y); o[2] = bfr(v.z); o[3] = bfr(v.w);
      reinterpret_cast<u16x4*>(xb)[i] = o;
    }
  } else {
    const float* src; u16b* dst; int C, lb;
    if (bid < 2048 + 768) { src = w_attn; dst = waT; C = 3072; lb = bid - 2048; }
    else                  { src = w_proj; dst = wpT; C = 1024; lb = bid - 2816; }
    const int R = 1024;
    const int nc = C >> 6;
    const int br = lb / nc, bc = lb % nc;
    const int r0 = br << 6, c0 = bc << 6;
    const int c = threadIdx.x & 63, r4 = threadIdx.x >> 6;
    #pragma unroll
    for (int i = 0; i < 16; ++i) {
      const int r = r4 + 4 * i;
      tile[r][c] = bfr(src[(size_t)(r0 + r) * C + c0 + c]);
    }
    __syncthreads();
    #pragma unroll
    for (int i = 0; i < 16; ++i) {
      const int rr = r4 + 4 * i;
      dst[(size_t)(c0 + rr) * R + r0 + c] = tile[c][rr];
    }
  }
}

// ---------------- 128x128 tile bf16 GEMM: BK=64 dbuf + XCD/8x4 L2 supertile + NT stores ----------------
// Supertile 8 brows x 4 bcols = 3 MB resident working set (< 4 MB L2 with headroom for
// the NT'd write stream) — was 8x8 = 4 MB exactly, which still thrashed A-panels.
template <int EPI>
__global__ __launch_bounds__(256, 2) void gemm128_kernel(
    const u16b* __restrict__ A, const u16b* __restrict__ Bt,
    const float* __restrict__ bias,
    u16b* __restrict__ oQ, u16b* __restrict__ oK, u16b* __restrict__ oVt,
    float* __restrict__ oF, int M, int N, int K) {
  __shared__ u16b smem[32768];  // 64 KB: 2 buf x (As 16KB + Bs 16KB); epilogue reuses 32KB
  const int tid = threadIdx.x;
  const int wid = tid >> 6, lane = tid & 63;
  const int xcd = blockIdx.x & 7;
  const int idx = blockIdx.x >> 3;
  const int stg = idx >> 5, r32 = idx & 31;           // supertile group of 4 bcols
  const int brow = (xcd << 3) + (r32 >> 2);
  const int bcol = (stg << 2) + (r32 & 3);
  const int wr = (wid >> 1) << 6, wc = (wid & 1) << 6;

  f32x4 acc[4][4] = {};

  const int srow = (wid << 5) + (lane >> 3);
  const int sc = ((lane & 7) ^ (lane >> 3)) << 3;
  const u16b* Ab = A + (size_t)((brow << 7) + srow) * K + sc;
  const u16b* Bb = Bt + (size_t)((bcol << 7) + srow) * K + sc;
  const int fr = lane & 15;
  const int fq = lane >> 4;
  const int pcs0 = ((fq) ^ (fr & 7)) << 4;
  const int pcs1 = ((4 + fq) ^ (fr & 7)) << 4;
  const int nk = K >> 6;

#define STAGE(bufi, kk)                                                        \
  {                                                                            \
    char* sb = (char*)smem + (bufi) * 32768;                                   \
    _Pragma("unroll")                                                          \
    for (int j = 0; j < 4; ++j)                                                \
      GLDS(Ab + (size_t)8 * K * j + (kk), sb + wid * 4096 + j * 1024);         \
    _Pragma("unroll")                                                          \
    for (int j = 0; j < 4; ++j)                                                \
      GLDS(Bb + (size_t)8 * K * j + (kk), sb + 16384 + wid * 4096 + j * 1024); \
  }

  STAGE(0, 0);
  STAGE(1, 64);

  #pragma unroll 1
  for (int kt = 0; kt < nk; ++kt) {
    if (kt + 1 < nk) asm volatile("s_waitcnt vmcnt(8)" ::: "memory");
    else             asm volatile("s_waitcnt vmcnt(0)" ::: "memory");
    __builtin_amdgcn_s_barrier();

    const char* As = (const char*)smem + (kt & 1) * 32768;
    const char* Bs = As + 16384;
    bf16x8 af0[4], af1[4], bf0[4], bf1[4];
    #pragma unroll
    for (int i = 0; i < 4; ++i) {
      const int rowb = (wr + i * 16 + fr) * 128;
      af0[i] = *(const bf16x8*)(As + rowb + pcs0);
      af1[i] = *(const bf16x8*)(As + rowb + pcs1);
    }
    #pragma unroll
    for (int j = 0; j < 4; ++j) {
      const int rowb = (wc + j * 16 + fr) * 128;
      bf0[j] = *(const bf16x8*)(Bs + rowb + pcs0);
      bf1[j] = *(const bf16x8*)(Bs + rowb + pcs1);
    }
    __builtin_amdgcn_s_setprio(1);
    #pragma unroll
    for (int i = 0; i < 4; ++i)
      #pragma unroll
      for (int j = 0; j < 4; ++j)
        acc[i][j] = __builtin_amdgcn_mfma_f32_16x16x32_bf16(af0[i], bf0[j], acc[i][j], 0, 0, 0);
    #pragma unroll
    for (int i = 0; i < 4; ++i)
      #pragma unroll
      for (int j = 0; j < 4; ++j)
        acc[i][j] = __builtin_amdgcn_mfma_f32_16x16x32_bf16(af1[i], bf1[j], acc[i][j], 0, 0, 0);
    __builtin_amdgcn_s_setprio(0);

    __builtin_amdgcn_s_barrier();
    if (kt + 2 < nk) STAGE(kt & 1, (kt + 2) << 6);
  }
#undef STAGE

  if (EPI == 1) {
    #pragma unroll
    for (int j = 0; j < 4; ++j) {
      const int n0 = (bcol << 7) + wc + j * 16 + fr;
      const float bv = bias[n0];
      #pragma unroll
      for (int i = 0; i < 4; ++i) {
        #pragma unroll
        for (int r = 0; r < 4; ++r) {
          const int m0 = (brow << 7) + wr + i * 16 + fq * 4 + r;
          __builtin_nontemporal_store(acc[i][j][r] + bv, &oF[(size_t)m0 * N + n0]);
        }
      }
    }
  } else {
    const int sect = bcol >> 3;  // 0:Q 1:K 2:V (block-uniform)
    if (sect < 2) {
      const float qs = (sect == 0) ? 0.1803368801f : 1.0f;  // 1/sqrt(64)*log2(e) in Q
      u16b* oPtr = (sect == 0) ? oQ : oK;
      u16b* tile = (u16b*)smem;
      #pragma unroll
      for (int j = 0; j < 4; ++j) {
        const int n = wc + j * 16 + fr;
        const float bv = bias[(bcol << 7) + n];
        #pragma unroll
        for (int i = 0; i < 4; ++i) {
          #pragma unroll
          for (int r = 0; r < 4; ++r) {
            const int m = wr + i * 16 + fq * 4 + r;
            const int byteoff = m * 256 + (((n >> 3) ^ (m & 7)) << 4) + ((n & 7) << 1);
            *(u16b*)((char*)tile + byteoff) = bfr((acc[i][j][r] + bv) * qs);
          }
        }
      }
      __syncthreads();
      const int nh = wid >> 1;
      const int c = lane & 7;
      #pragma unroll
      for (int it = 0; it < 8; ++it) {
        const int m = ((wid & 1) << 6) + (it << 3) + (lane >> 3);
        const int chunk = (nh << 3) + (c ^ (m & 7));
        const bf16x8 val = *(const bf16x8*)((const char*)tile + m * 256 + chunk * 16);
        const int m0 = (brow << 7) + m;
        const int n0 = (bcol << 7) + (nh << 6) + (c << 3);
        const int bb = m0 >> 11, tt = m0 & 2047;
        const int h = (n0 >> 6) & 15, d = n0 & 63;
        __builtin_nontemporal_store(val,
            (bf16x8*)(oPtr + (((size_t)(bb * 16 + h) * 2048 + tt) * 64 + d)));
      }
    } else {
      // V: LDS tile TRANSPOSED [nl 128][m 128] swizzled, store Vt[bh][d][t] rows
      u16b* tile = (u16b*)smem;
      #pragma unroll
      for (int j = 0; j < 4; ++j) {
        const int nl = wc + j * 16 + fr;
        const float bv = bias[(bcol << 7) + nl];
        #pragma unroll
        for (int i = 0; i < 4; ++i) {
          #pragma unroll
          for (int r = 0; r < 4; ++r) {
            const int m = wr + i * 16 + fq * 4 + r;
            const int byteoff = nl * 256 + (((m >> 3) ^ (nl & 7)) << 4) + ((m & 7) << 1);
            *(u16b*)((char*)tile + byteoff) = bfr(acc[i][j][r] + bv);
          }
        }
      }
      __syncthreads();
      const int row0 = wid << 5;
      const int c16 = lane & 15;
      const int rw = lane >> 4;
      const int t0 = (brow << 7) & 2047;
      const int bb = brow >> 4;
      #pragma unroll
      for (int it = 0; it < 8; ++it) {
        const int nl = row0 + (it << 2) + rw;
        const int pch = c16 ^ (nl & 7);
        const bf16x8 val = *(const bf16x8*)((const char*)tile + nl * 256 + pch * 16);
        const int h = ((bcol & 7) << 1) + (nl >> 6);
        const int d = nl & 63;
        __builtin_nontemporal_store(val,
            (bf16x8*)(oVt + ((size_t)((bb << 4) + h) * 64 + d) * 2048 + t0 + (c16 << 3)));
      }
    }
  }
}

// ---------------- flash attention: swapped 32x32, KVBLK=64, 3-buffer SINGLE-BARRIER ----------------
__global__ __launch_bounds__(256, 3) void flash_kernel(
    const u16b* __restrict__ Q, const u16b* __restrict__ K,
    const u16b* __restrict__ Vt, u16b* __restrict__ O) {
  __shared__ u16b smem[24576];  // 48KB: 3 x (K 8KB + V 8KB)
  const int bid = blockIdx.x;
  const int bh = bid & 63;
  const int qt = 15 - (bid >> 6);  // heavy q-tiles dispatch first
  const int tid = threadIdx.x, wid = tid >> 6, lane = tid & 63;
  const int ln31 = lane & 31, hi = lane >> 5;
  const size_t baseQK = (size_t)bh * 2048 * 64;
  const size_t baseV = (size_t)bh * 64 * 2048;
  const int b = bh >> 4, h = bh & 15;
  const int srow = wid * 8 + (lane >> 3);
  const int sc = ((lane & 7) ^ (srow & 7)) << 3;

  const int q0w = (qt << 7) + wid * 32;
  const int NT = 2 * qt + 2;
  const int LT = q0w >> 6;

#define FSTAGE(kt, bi)                                                         \
  {                                                                            \
    char* kb_ = (char*)smem + (bi) * 16384;                                    \
    const int k0_ = (kt) << 6;                                                 \
    GLDS(K + baseQK + (size_t)(k0_ + srow) * 64 + sc,        kb_ + wid * 1024);\
    GLDS(K + baseQK + (size_t)(k0_ + 32 + srow) * 64 + sc,   kb_ + 4096 + wid * 1024);\
    GLDS(Vt + baseV + (size_t)srow * 2048 + k0_ + sc,        kb_ + 8192 + wid * 1024);\
    GLDS(Vt + baseV + (size_t)(32 + srow) * 2048 + k0_ + sc, kb_ + 12288 + wid * 1024);\
  }

  bf16x8 qf[4];
  {
    const u16b* qp = Q + baseQK + (size_t)(q0w + ln31) * 64 + hi * 8;
    #pragma unroll
    for (int kk = 0; kk < 4; ++kk) qf[kk] = *(const bf16x8*)(qp + kk * 16);
  }
  bf16x8 ones;
  {
    union { u16b s[8]; bf16x8 v; } o1;
    #pragma unroll
    for (int i = 0; i < 8; ++i) o1.s[i] = 0x3F80;  // bf16 1.0
    ones = o1.v;
  }

  f32x16 oa0 = {}, oa1 = {}, lacc = {};

  FSTAGE(0, 0);
  FSTAGE(1, 1);

  int buf = 0;       // kt % 3
  int nbuf = 2;      // (kt+2) % 3
  #pragma unroll 1
  for (int kt = 0; kt < NT; ++kt) {
    if (kt + 1 < NT) asm volatile("s_waitcnt vmcnt(4)" ::: "memory");
    else             asm volatile("s_waitcnt vmcnt(0)" ::: "memory");
    __builtin_amdgcn_s_barrier();

    if (kt + 2 < NT) FSTAGE(kt + 2, nbuf);  // issue early: hides under compute

    if (kt <= LT) {
      const char* kb = (const char*)smem + buf * 16384;
      const char* vb = kb + 8192;
      const bool diag = (kt == LT);
      const int maxsub = diag ? (wid & 1) : 1;  // wave-uniform

      f32x16 s[2] = {};
      __builtin_amdgcn_s_setprio(1);
      #pragma unroll
      for (int ss = 0; ss < 2; ++ss) {
        if (ss <= maxsub) {
          const int row = 32 * ss + ln31;
          #pragma unroll
          for (int kk = 0; kk < 4; ++kk) {
            const int ch = (2 * kk + hi) ^ (row & 7);
            const bf16x8 kf = *(const bf16x8*)(kb + row * 128 + ch * 16);
            s[ss] = __builtin_amdgcn_mfma_f32_32x32x16_bf16(kf, qf[kk], s[ss], 0, 0, 0);
          }
        }
      }
      __builtin_amdgcn_s_setprio(0);

      if (diag) {
        #pragma unroll
        for (int ss = 0; ss < 2; ++ss) {
          if (ss == (wid & 1)) {
            #pragma unroll
            for (int r = 0; r < 16; ++r) {
              const int kvr = (r & 3) + 8 * (r >> 2) + 4 * hi;
              if (kvr > ln31) s[ss][r] = -3e38f;
            }
          }
        }
      }

      #pragma unroll
      for (int ss = 0; ss < 2; ++ss) {
        if (ss <= maxsub) {
          #pragma unroll
          for (int r = 0; r < 16; ++r)
            s[ss][r] = __builtin_amdgcn_exp2f(s[ss][r]);
        }
      }

      union WB { unsigned u[4]; bf16x8 v; };
      __builtin_amdgcn_s_setprio(1);
      #pragma unroll
      for (int ss = 0; ss < 2; ++ss) {
        if (ss <= maxsub) {
          WB pA, pB;
#define MKPA(W0, W1, W2, W3, P0, P1, P2, P3, P4, P5, P6, P7)                 \
          {                                                                   \
            unsigned a0 = pk2(P0, P1), a1 = pk2(P2, P3);                      \
            unsigned b0 = pk2(P4, P5), b1 = pk2(P6, P7);                      \
            auto r0 = __builtin_amdgcn_permlane32_swap(a0, b0, false, false); \
            auto r1 = __builtin_amdgcn_permlane32_swap(a1, b1, false, false); \
            unsigned o0[2], o1[2];                                            \
            __builtin_memcpy(o0, &r0, 8); __builtin_memcpy(o1, &r1, 8);       \
            W0 = o0[0]; W2 = o0[1]; W1 = o1[0]; W3 = o1[1];                   \
          }
          MKPA(pA.u[0], pA.u[1], pA.u[2], pA.u[3],
               s[ss][0], s[ss][1], s[ss][2], s[ss][3],
               s[ss][4], s[ss][5], s[ss][6], s[ss][7]);
          MKPA(pB.u[0], pB.u[1], pB.u[2], pB.u[3],
               s[ss][8], s[ss][9], s[ss][10], s[ss][11],
               s[ss][12], s[ss][13], s[ss][14], s[ss][15]);
#undef MKPA
          const int r0v = ln31, r1v = 32 + ln31;
          const char* v0 = vb + r0v * 128;
          const char* v1 = vb + r1v * 128;
          const int chA0 = ((4 * ss + hi) ^ (r0v & 7)) << 4;
          const int chA1 = ((4 * ss + hi) ^ (r1v & 7)) << 4;
          const int chB0 = ((4 * ss + 2 + hi) ^ (r0v & 7)) << 4;
          const int chB1 = ((4 * ss + 2 + hi) ^ (r1v & 7)) << 4;
          lacc = __builtin_amdgcn_mfma_f32_32x32x16_bf16(ones, pA.v, lacc, 0, 0, 0);
          oa0 = __builtin_amdgcn_mfma_f32_32x32x16_bf16(*(const bf16x8*)(v0 + chA0), pA.v, oa0, 0, 0, 0);
          oa1 = __builtin_amdgcn_mfma_f32_32x32x16_bf16(*(const bf16x8*)(v1 + chA1), pA.v, oa1, 0, 0, 0);
          lacc = __builtin_amdgcn_mfma_f32_32x32x16_bf16(ones, pB.v, lacc, 0, 0, 0);
          oa0 = __builtin_amdgcn_mfma_f32_32x32x16_bf16(*(const bf16x8*)(v0 + chB0), pB.v, oa0, 0, 0, 0);
          oa1 = __builtin_amdgcn_mfma_f32_32x32x16_bf16(*(const bf16x8*)(v1 + chB1), pB.v, oa1, 0, 0, 0);
        }
      }
      __builtin_amdgcn_s_setprio(0);
    }

    buf = (buf == 2) ? 0 : buf + 1;
    nbuf = (nbuf == 2) ? 0 : nbuf + 1;
  }

  const float inv = 1.0f / lacc[0];
  const int q = q0w + ln31;
  u16b* orow = O + (size_t)(b * 2048 + q) * 1024 + h * 64;
  #pragma unroll
  for (int rq = 0; rq < 4; ++rq) {
    u16x4 v0, v1;
    #pragma unroll
    for (int j = 0; j < 4; ++j) {
      v0[j] = bfr(oa0[4 * rq + j] * inv);
      v1[j] = bfr(oa1[4 * rq + j] * inv);
    }
    const int d0 = 8 * rq + 4 * hi;
    __builtin_nontemporal_store(v0, (u16x4*)(orow + d0));
    __builtin_nontemporal_store(v1, (u16x4*)(orow + 32 + d0));
  }
#undef FSTAGE
}

extern "C" void kernel_launch(void* const* d_in, const int* in_sizes, int n_in,
                              void* d_out, int out_size, void* d_ws, size_t ws_size,
                              hipStream_t stream) {
  const float* x      = (const float*)d_in[0];
  const float* w_attn = (const float*)d_in[1];
  const float* b_attn = (const float*)d_in[2];
  const float* w_proj = (const float*)d_in[3];
  const float* b_proj = (const float*)d_in[4];
  float* out = (float*)d_out;
  char* ws = (char*)d_ws;

  u16b* xb  = (u16b*)(ws + 0);          // [8192][1024] bf16 x; later reused as attn_out
  u16b* waT = (u16b*)(ws + 16777216);   // [3072][1024] w_attn^T bf16
  u16b* wpT = (u16b*)(ws + 23068672);   // [1024][1024] w_proj^T bf16
  u16b* Qb  = (u16b*)(ws + 25165824);   // [64 bh][2048][64]
  u16b* Kb  = (u16b*)(ws + 41943040);
  u16b* Vtb = (u16b*)(ws + 75497472);   // [64 bh][64 d][2048 t] (written by qkv GEMM)
  u16b* attn = xb;

  prep_kernel<<<3072, 256, 0, stream>>>(x, xb, w_attn, waT, w_proj, wpT);
  gemm128_kernel<0><<<64 * 24, 256, 0, stream>>>(xb, waT, b_attn, Qb, Kb, Vtb, nullptr,
                                                 8192, 3072, 1024);
  flash_kernel<<<1024, 256, 0, stream>>>(Qb, Kb, Vtb, attn);
  gemm128_kernel<1><<<64 * 8, 256, 0, stream>>>(attn, wpT, b_proj, nullptr, nullptr, nullptr,
                                                out, 8192, 1024, 1024);
}

// Round 21
// 143.474 us; speedup vs baseline: 1.0981x; 1.0981x over previous
//
#include <hip/hip_runtime.h>

// CausalSelfAttention: B=4, T=2048, C=1024, H=16, D=64
// Pipeline: fused prep (x->bf16 + both weight transposes)
//           -> qkv GEMM (BK=64 dbuf 2-barrier, XCD+8x8 L2 supertile, NT epilogue stores)
//           -> flash attn (swapped 32x32, KVBLK=64, fixed-shift, l-via-MFMA,
//              3-buffer single-barrier, PLAIN output stores) -> proj GEMM
// Round-19 exact (best measured: 143.9 us). Round-20's flash NT stores caused 3.2x
// write amplification (8B/lane scattered stores need L2 write-combining) — reverted.

typedef unsigned short u16b;
typedef __bf16 bf16x8 __attribute__((ext_vector_type(8)));
typedef float f32x4 __attribute__((ext_vector_type(4)));
typedef float f32x16 __attribute__((ext_vector_type(16)));
typedef unsigned short u16x4 __attribute__((ext_vector_type(4)));

#define AS1(p) ((const __attribute__((address_space(1))) void*)(p))
#define AS3(p) ((__attribute__((address_space(3))) void*)(p))
#define GLDS(g, l) __builtin_amdgcn_global_load_lds(AS1(g), AS3(l), 16, 0, 0)

__device__ __forceinline__ u16b bfr(float v) {  // f32 -> bf16 bits, RNE
  union { float f; unsigned u; } x; x.f = v;
  unsigned r = x.u + 0x7fffu + ((x.u >> 16) & 1u);
  return (u16b)(r >> 16);
}

__device__ __forceinline__ unsigned pk2(float lo, float hi) {  // pack 2 f32 -> 2 bf16 in u32
  union { __bf16 h[2]; unsigned u; } t;
  t.h[0] = (__bf16)lo; t.h[1] = (__bf16)hi;
  return t.u;
}

// ---------------- fused prep: x cvt (blocks 0..2047) + w transposes (2048..3071) ----------------
__global__ __launch_bounds__(256) void prep_kernel(
    const float* __restrict__ x, u16b* __restrict__ xb,
    const float* __restrict__ w_attn, u16b* __restrict__ waT,
    const float* __restrict__ w_proj, u16b* __restrict__ wpT) {
  __shared__ u16b tile[64][72];
  const int bid = blockIdx.x;
  if (bid < 2048) {
    const int n4 = (8192 * 1024) / 4;
    const int stride = 2048 * 256;
    for (int i = bid * 256 + threadIdx.x; i < n4; i += stride) {
      const float4 v = reinterpret_cast<const float4*>(x)[i];
      u16x4 o;
      o[0] = bfr(v.x); o[1] = bfr(v.y); o[2] = bfr(v.z); o[3] = bfr(v.w);
      reinterpret_cast<u16x4*>(xb)[i] = o;
    }
  } else {
    const float* src; u16b* dst; int C, lb;
    if (bid < 2048 + 768) { src = w_attn; dst = waT; C = 3072; lb = bid - 2048; }
    else                  { src = w_proj; dst = wpT; C = 1024; lb = bid - 2816; }
    const int R = 1024;
    const int nc = C >> 6;
    const int br = lb / nc, bc = lb % nc;
    const int r0 = br << 6, c0 = bc << 6;
    const int c = threadIdx.x & 63, r4 = threadIdx.x >> 6;
    #pragma unroll
    for (int i = 0; i < 16; ++i) {
      const int r = r4 + 4 * i;
      tile[r][c] = bfr(src[(size_t)(r0 + r) * C + c0 + c]);
    }
    __syncthreads();
    #pragma unroll
    for (int i = 0; i < 16; ++i) {
      const int rr = r4 + 4 * i;
      dst[(size_t)(c0 + rr) * R + r0 + c] = tile[c][rr];
    }
  }
}

// ---------------- 128x128 tile bf16 GEMM: BK=64 dbuf + XCD/8x8 L2 supertile + NT stores ----------------
template <int EPI>
__global__ __launch_bounds__(256, 2) void gemm128_kernel(
    const u16b* __restrict__ A, const u16b* __restrict__ Bt,
    const float* __restrict__ bias,
    u16b* __restrict__ oQ, u16b* __restrict__ oK, u16b* __restrict__ oVt,
    float* __restrict__ oF, int M, int N, int K) {
  __shared__ u16b smem[32768];  // 64 KB: 2 buf x (As 16KB + Bs 16KB); epilogue reuses 32KB
  const int tid = threadIdx.x;
  const int wid = tid >> 6, lane = tid & 63;
  const int xcd = blockIdx.x & 7;
  const int idx = blockIdx.x >> 3;
  const int stg = idx >> 6, rr6 = idx & 63;
  const int brow = (xcd << 3) + (rr6 >> 3);
  const int bcol = (stg << 3) + (rr6 & 7);
  const int wr = (wid >> 1) << 6, wc = (wid & 1) << 6;

  f32x4 acc[4][4] = {};

  const int srow = (wid << 5) + (lane >> 3);
  const int sc = ((lane & 7) ^ (lane >> 3)) << 3;
  const u16b* Ab = A + (size_t)((brow << 7) + srow) * K + sc;
  const u16b* Bb = Bt + (size_t)((bcol << 7) + srow) * K + sc;
  const int fr = lane & 15;
  const int fq = lane >> 4;
  const int pcs0 = ((fq) ^ (fr & 7)) << 4;
  const int pcs1 = ((4 + fq) ^ (fr & 7)) << 4;
  const int nk = K >> 6;

#define STAGE(bufi, kk)                                                        \
  {                                                                            \
    char* sb = (char*)smem + (bufi) * 32768;                                   \
    _Pragma("unroll")                                                          \
    for (int j = 0; j < 4; ++j)                                                \
      GLDS(Ab + (size_t)8 * K * j + (kk), sb + wid * 4096 + j * 1024);         \
    _Pragma("unroll")                                                          \
    for (int j = 0; j < 4; ++j)                                                \
      GLDS(Bb + (size_t)8 * K * j + (kk), sb + 16384 + wid * 4096 + j * 1024); \
  }

  STAGE(0, 0);
  STAGE(1, 64);

  #pragma unroll 1
  for (int kt = 0; kt < nk; ++kt) {
    if (kt + 1 < nk) asm volatile("s_waitcnt vmcnt(8)" ::: "memory");
    else             asm volatile("s_waitcnt vmcnt(0)" ::: "memory");
    __builtin_amdgcn_s_barrier();

    const char* As = (const char*)smem + (kt & 1) * 32768;
    const char* Bs = As + 16384;
    bf16x8 af0[4], af1[4], bf0[4], bf1[4];
    #pragma unroll
    for (int i = 0; i < 4; ++i) {
      const int rowb = (wr + i * 16 + fr) * 128;
      af0[i] = *(const bf16x8*)(As + rowb + pcs0);
      af1[i] = *(const bf16x8*)(As + rowb + pcs1);
    }
    #pragma unroll
    for (int j = 0; j < 4; ++j) {
      const int rowb = (wc + j * 16 + fr) * 128;
      bf0[j] = *(const bf16x8*)(Bs + rowb + pcs0);
      bf1[j] = *(const bf16x8*)(Bs + rowb + pcs1);
    }
    __builtin_amdgcn_s_setprio(1);
    #pragma unroll
    for (int i = 0; i < 4; ++i)
      #pragma unroll
      for (int j = 0; j < 4; ++j)
        acc[i][j] = __builtin_amdgcn_mfma_f32_16x16x32_bf16(af0[i], bf0[j], acc[i][j], 0, 0, 0);
    #pragma unroll
    for (int i = 0; i < 4; ++i)
      #pragma unroll
      for (int j = 0; j < 4; ++j)
        acc[i][j] = __builtin_amdgcn_mfma_f32_16x16x32_bf16(af1[i], bf1[j], acc[i][j], 0, 0, 0);
    __builtin_amdgcn_s_setprio(0);

    __builtin_amdgcn_s_barrier();
    if (kt + 2 < nk) STAGE(kt & 1, (kt + 2) << 6);
  }
#undef STAGE

  if (EPI == 1) {
    #pragma unroll
    for (int j = 0; j < 4; ++j) {
      const int n0 = (bcol << 7) + wc + j * 16 + fr;
      const float bv = bias[n0];
      #pragma unroll
      for (int i = 0; i < 4; ++i) {
        #pragma unroll
        for (int r = 0; r < 4; ++r) {
          const int m0 = (brow << 7) + wr + i * 16 + fq * 4 + r;
          __builtin_nontemporal_store(acc[i][j][r] + bv, &oF[(size_t)m0 * N + n0]);
        }
      }
    }
  } else {
    const int sect = bcol >> 3;  // 0:Q 1:K 2:V (block-uniform)
    if (sect < 2) {
      const float qs = (sect == 0) ? 0.1803368801f : 1.0f;  // 1/sqrt(64)*log2(e) in Q
      u16b* oPtr = (sect == 0) ? oQ : oK;
      u16b* tile = (u16b*)smem;
      #pragma unroll
      for (int j = 0; j < 4; ++j) {
        const int n = wc + j * 16 + fr;
        const float bv = bias[(bcol << 7) + n];
        #pragma unroll
        for (int i = 0; i < 4; ++i) {
          #pragma unroll
          for (int r = 0; r < 4; ++r) {
            const int m = wr + i * 16 + fq * 4 + r;
            const int byteoff = m * 256 + (((n >> 3) ^ (m & 7)) << 4) + ((n & 7) << 1);
            *(u16b*)((char*)tile + byteoff) = bfr((acc[i][j][r] + bv) * qs);
          }
        }
      }
      __syncthreads();
      const int nh = wid >> 1;
      const int c = lane & 7;
      #pragma unroll
      for (int it = 0; it < 8; ++it) {
        const int m = ((wid & 1) << 6) + (it << 3) + (lane >> 3);
        const int chunk = (nh << 3) + (c ^ (m & 7));
        const bf16x8 val = *(const bf16x8*)((const char*)tile + m * 256 + chunk * 16);
        const int m0 = (brow << 7) + m;
        const int n0 = (bcol << 7) + (nh << 6) + (c << 3);
        const int bb = m0 >> 11, tt = m0 & 2047;
        const int h = (n0 >> 6) & 15, d = n0 & 63;
        __builtin_nontemporal_store(val,
            (bf16x8*)(oPtr + (((size_t)(bb * 16 + h) * 2048 + tt) * 64 + d)));
      }
    } else {
      // V: LDS tile TRANSPOSED [nl 128][m 128] swizzled, store Vt[bh][d][t] rows
      u16b* tile = (u16b*)smem;
      #pragma unroll
      for (int j = 0; j < 4; ++j) {
        const int nl = wc + j * 16 + fr;
        const float bv = bias[(bcol << 7) + nl];
        #pragma unroll
        for (int i = 0; i < 4; ++i) {
          #pragma unroll
          for (int r = 0; r < 4; ++r) {
            const int m = wr + i * 16 + fq * 4 + r;
            const int byteoff = nl * 256 + (((m >> 3) ^ (nl & 7)) << 4) + ((m & 7) << 1);
            *(u16b*)((char*)tile + byteoff) = bfr(acc[i][j][r] + bv);
          }
        }
      }
      __syncthreads();
      const int row0 = wid << 5;
      const int c16 = lane & 15;
      const int rw = lane >> 4;
      const int t0 = (brow << 7) & 2047;
      const int bb = brow >> 4;
      #pragma unroll
      for (int it = 0; it < 8; ++it) {
        const int nl = row0 + (it << 2) + rw;
        const int pch = c16 ^ (nl & 7);
        const bf16x8 val = *(const bf16x8*)((const char*)tile + nl * 256 + pch * 16);
        const int h = ((bcol & 7) << 1) + (nl >> 6);
        const int d = nl & 63;
        __builtin_nontemporal_store(val,
            (bf16x8*)(oVt + ((size_t)((bb << 4) + h) * 64 + d) * 2048 + t0 + (c16 << 3)));
      }
    }
  }
}

// ---------------- flash attention: swapped 32x32, KVBLK=64, 3-buffer SINGLE-BARRIER ----------------
__global__ __launch_bounds__(256, 3) void flash_kernel(
    const u16b* __restrict__ Q, const u16b* __restrict__ K,
    const u16b* __restrict__ Vt, u16b* __restrict__ O) {
  __shared__ u16b smem[24576];  // 48KB: 3 x (K 8KB + V 8KB)
  const int bid = blockIdx.x;
  const int bh = bid & 63;
  const int qt = 15 - (bid >> 6);  // heavy q-tiles dispatch first
  const int tid = threadIdx.x, wid = tid >> 6, lane = tid & 63;
  const int ln31 = lane & 31, hi = lane >> 5;
  const size_t baseQK = (size_t)bh * 2048 * 64;
  const size_t baseV = (size_t)bh * 64 * 2048;
  const int b = bh >> 4, h = bh & 15;
  const int srow = wid * 8 + (lane >> 3);
  const int sc = ((lane & 7) ^ (srow & 7)) << 3;

  const int q0w = (qt << 7) + wid * 32;
  const int NT = 2 * qt + 2;
  const int LT = q0w >> 6;

#define FSTAGE(kt, bi)                                                         \
  {                                                                            \
    char* kb_ = (char*)smem + (bi) * 16384;                                    \
    const int k0_ = (kt) << 6;                                                 \
    GLDS(K + baseQK + (size_t)(k0_ + srow) * 64 + sc,        kb_ + wid * 1024);\
    GLDS(K + baseQK + (size_t)(k0_ + 32 + srow) * 64 + sc,   kb_ + 4096 + wid * 1024);\
    GLDS(Vt + baseV + (size_t)srow * 2048 + k0_ + sc,        kb_ + 8192 + wid * 1024);\
    GLDS(Vt + baseV + (size_t)(32 + srow) * 2048 + k0_ + sc, kb_ + 12288 + wid * 1024);\
  }

  bf16x8 qf[4];
  {
    const u16b* qp = Q + baseQK + (size_t)(q0w + ln31) * 64 + hi * 8;
    #pragma unroll
    for (int kk = 0; kk < 4; ++kk) qf[kk] = *(const bf16x8*)(qp + kk * 16);
  }
  bf16x8 ones;
  {
    union { u16b s[8]; bf16x8 v; } o1;
    #pragma unroll
    for (int i = 0; i < 8; ++i) o1.s[i] = 0x3F80;  // bf16 1.0
    ones = o1.v;
  }

  f32x16 oa0 = {}, oa1 = {}, lacc = {};

  FSTAGE(0, 0);
  FSTAGE(1, 1);

  int buf = 0;       // kt % 3
  int nbuf = 2;      // (kt+2) % 3
  #pragma unroll 1
  for (int kt = 0; kt < NT; ++kt) {
    if (kt + 1 < NT) asm volatile("s_waitcnt vmcnt(4)" ::: "memory");
    else             asm volatile("s_waitcnt vmcnt(0)" ::: "memory");
    __builtin_amdgcn_s_barrier();

    if (kt + 2 < NT) FSTAGE(kt + 2, nbuf);  // issue early: hides under compute

    if (kt <= LT) {
      const char* kb = (const char*)smem + buf * 16384;
      const char* vb = kb + 8192;
      const bool diag = (kt == LT);
      const int maxsub = diag ? (wid & 1) : 1;  // wave-uniform

      f32x16 s[2] = {};
      __builtin_amdgcn_s_setprio(1);
      #pragma unroll
      for (int ss = 0; ss < 2; ++ss) {
        if (ss <= maxsub) {
          const int row = 32 * ss + ln31;
          #pragma unroll
          for (int kk = 0; kk < 4; ++kk) {
            const int ch = (2 * kk + hi) ^ (row & 7);
            const bf16x8 kf = *(const bf16x8*)(kb + row * 128 + ch * 16);
            s[ss] = __builtin_amdgcn_mfma_f32_32x32x16_bf16(kf, qf[kk], s[ss], 0, 0, 0);
          }
        }
      }
      __builtin_amdgcn_s_setprio(0);

      if (diag) {
        #pragma unroll
        for (int ss = 0; ss < 2; ++ss) {
          if (ss == (wid & 1)) {
            #pragma unroll
            for (int r = 0; r < 16; ++r) {
              const int kvr = (r & 3) + 8 * (r >> 2) + 4 * hi;
              if (kvr > ln31) s[ss][r] = -3e38f;
            }
          }
        }
      }

      #pragma unroll
      for (int ss = 0; ss < 2; ++ss) {
        if (ss <= maxsub) {
          #pragma unroll
          for (int r = 0; r < 16; ++r)
            s[ss][r] = __builtin_amdgcn_exp2f(s[ss][r]);
        }
      }

      union WB { unsigned u[4]; bf16x8 v; };
      __builtin_amdgcn_s_setprio(1);
      #pragma unroll
      for (int ss = 0; ss < 2; ++ss) {
        if (ss <= maxsub) {
          WB pA, pB;
#define MKPA(W0, W1, W2, W3, P0, P1, P2, P3, P4, P5, P6, P7)                 \
          {                                                                   \
            unsigned a0 = pk2(P0, P1), a1 = pk2(P2, P3);                      \
            unsigned b0 = pk2(P4, P5), b1 = pk2(P6, P7);                      \
            auto r0 = __builtin_amdgcn_permlane32_swap(a0, b0, false, false); \
            auto r1 = __builtin_amdgcn_permlane32_swap(a1, b1, false, false); \
            unsigned o0[2], o1[2];                                            \
            __builtin_memcpy(o0, &r0, 8); __builtin_memcpy(o1, &r1, 8);       \
            W0 = o0[0]; W2 = o0[1]; W1 = o1[0]; W3 = o1[1];                   \
          }
          MKPA(pA.u[0], pA.u[1], pA.u[2], pA.u[3],
               s[ss][0], s[ss][1], s[ss][2], s[ss][3],
               s[ss][4], s[ss][5], s[ss][6], s[ss][7]);
          MKPA(pB.u[0], pB.u[1], pB.u[2], pB.u[3],
               s[ss][8], s[ss][9], s[ss][10], s[ss][11],
               s[ss][12], s[ss][13], s[ss][14], s[ss][15]);
#undef MKPA
          const int r0v = ln31, r1v = 32 + ln31;
          const char* v0 = vb + r0v * 128;
          const char* v1 = vb + r1v * 128;
          const int chA0 = ((4 * ss + hi) ^ (r0v & 7)) << 4;
          const int chA1 = ((4 * ss + hi) ^ (r1v & 7)) << 4;
          const int chB0 = ((4 * ss + 2 + hi) ^ (r0v & 7)) << 4;
          const int chB1 = ((4 * ss + 2 + hi) ^ (r1v & 7)) << 4;
          lacc = __builtin_amdgcn_mfma_f32_32x32x16_bf16(ones, pA.v, lacc, 0, 0, 0);
          oa0 = __builtin_amdgcn_mfma_f32_32x32x16_bf16(*(const bf16x8*)(v0 + chA0), pA.v, oa0, 0, 0, 0);
          oa1 = __builtin_amdgcn_mfma_f32_32x32x16_bf16(*(const bf16x8*)(v1 + chA1), pA.v, oa1, 0, 0, 0);
          lacc = __builtin_amdgcn_mfma_f32_32x32x16_bf16(ones, pB.v, lacc, 0, 0, 0);
          oa0 = __builtin_amdgcn_mfma_f32_32x32x16_bf16(*(const bf16x8*)(v0 + chB0), pB.v, oa0, 0, 0, 0);
          oa1 = __builtin_amdgcn_mfma_f32_32x32x16_bf16(*(const bf16x8*)(v1 + chB1), pB.v, oa1, 0, 0, 0);
        }
      }
      __builtin_amdgcn_s_setprio(0);
    }

    buf = (buf == 2) ? 0 : buf + 1;
    nbuf = (nbuf == 2) ? 0 : nbuf + 1;
  }

  const float inv = 1.0f / lacc[0];
  const int q = q0w + ln31;
  u16b* orow = O + (size_t)(b * 2048 + q) * 1024 + h * 64;
  #pragma unroll
  for (int rq = 0; rq < 4; ++rq) {
    u16x4 v0, v1;
    #pragma unroll
    for (int j = 0; j < 4; ++j) {
      v0[j] = bfr(oa0[4 * rq + j] * inv);
      v1[j] = bfr(oa1[4 * rq + j] * inv);
    }
    const int d0 = 8 * rq + 4 * hi;
    *(u16x4*)(orow + d0) = v0;
    *(u16x4*)(orow + 32 + d0) = v1;
  }
#undef FSTAGE
}

extern "C" void kernel_launch(void* const* d_in, const int* in_sizes, int n_in,
                              void* d_out, int out_size, void* d_ws, size_t ws_size,
                              hipStream_t stream) {
  const float* x      = (const float*)d_in[0];
  const float* w_attn = (const float*)d_in[1];
  const float* b_attn = (const float*)d_in[2];
  const float* w_proj = (const float*)d_in[3];
  const float* b_proj = (const float*)d_in[4];
  float* out = (float*)d_out;
  char* ws = (char*)d_ws;

  u16b* xb  = (u16b*)(ws + 0);          // [8192][1024] bf16 x; later reused as attn_out
  u16b* waT = (u16b*)(ws + 16777216);   // [3072][1024] w_attn^T bf16
  u16b* wpT = (u16b*)(ws + 23068672);   // [1024][1024] w_proj^T bf16
  u16b* Qb  = (u16b*)(ws + 25165824);   // [64 bh][2048][64]
  u16b* Kb  = (u16b*)(ws + 41943040);
  u16b* Vtb = (u16b*)(ws + 75497472);   // [64 bh][64 d][2048 t] (written by qkv GEMM)
  u16b* attn = xb;

  prep_kernel<<<3072, 256, 0, stream>>>(x, xb, w_attn, waT, w_proj, wpT);
  gemm128_kernel<0><<<64 * 24, 256, 0, stream>>>(xb, waT, b_attn, Qb, Kb, Vtb, nullptr,
                                                 8192, 3072, 1024);
  flash_kernel<<<1024, 256, 0, stream>>>(Qb, Kb, Vtb, attn);
  gemm128_kernel<1><<<64 * 8, 256, 0, stream>>>(attn, wpT, b_proj, nullptr, nullptr, nullptr,
                                                out, 8192, 1024, 1024);
}